// Round 1
// baseline (299.489 us; speedup 1.0000x reference)
//
#include <hip/hip_runtime.h>
#include <hip/hip_bf16.h>

// NT-Xent loss, 2B=8192, D=128, T=0.5.
// sim = (N N^T) * 2 with N = row-normalized embeddings (bf16).
// logsumexp per row with FIXED max = 2.0 (cos<=1 -> logit<=2), masked
// entries (j==i, j==i^4096) contribute 0. picked logit computed in fp32.

typedef __bf16 bf16x8 __attribute__((ext_vector_type(8)));
typedef float floatx4 __attribute__((ext_vector_type(4)));

#define TWO_B 8192
#define B_HALF 4096
#define D 128
#define INV_T 2.0f            // 1/temperature
#define FIXED_MAX 2.0f        // logit upper bound
#define C_EXP 2.88539008177793f   // INV_T * log2(e) (and FIXED_MAX*log2e)

// ---------------- kernel 1: normalize rows, cast to bf16 -----------------
__global__ void k_normalize(const float* __restrict__ emb,
                            float* __restrict__ rnorm,
                            __bf16* __restrict__ nb) {
    int wv   = threadIdx.x >> 6;
    int lane = threadIdx.x & 63;
    int row  = blockIdx.x * 4 + wv;
    const float2* e2 = reinterpret_cast<const float2*>(emb + (size_t)row * D);
    float2 v = e2[lane];
    float ss = v.x * v.x + v.y * v.y;
#pragma unroll
    for (int off = 32; off >= 1; off >>= 1) ss += __shfl_xor(ss, off, 64);
    float rn = rsqrtf(fmaxf(ss, 1e-16f));
    __bf16* np = nb + (size_t)row * D + lane * 2;
    np[0] = (__bf16)(v.x * rn);
    np[1] = (__bf16)(v.y * rn);
    if (lane == 0) rnorm[row] = rn;
}

// ------- kernel 2: fused Gram-matrix MFMA + masked exp-sum per row -------
// grid: (8192/64 row-blocks, 4 col-splits), block: 256 (4 waves x 16 rows)
__global__ __launch_bounds__(256) void k_simlse(const __bf16* __restrict__ nb,
                                                float* __restrict__ l_arr) {
    const int lane = threadIdx.x & 63;
    const int w    = threadIdx.x >> 6;
    const int m    = lane & 15;
    const int quad = lane >> 4;
    const int row0 = blockIdx.x * 64 + w * 16;
    const int col_base = blockIdx.y * 2048;

    // A fragments: this wave's 16 rows, full K=128, kept in registers.
    bf16x8 a_frag[4];
#pragma unroll
    for (int kc = 0; kc < 4; ++kc)
        a_frag[kc] = *reinterpret_cast<const bf16x8*>(
            nb + (size_t)(row0 + m) * D + kc * 32 + quad * 8);

    float l_run[4] = {0.f, 0.f, 0.f, 0.f};
    const int i_base = row0 + quad * 4;  // rows owned by this lane in C layout

    for (int c0 = col_base; c0 < col_base + 2048; c0 += 64) {
        bf16x8 b_frag[4][4];
#pragma unroll
        for (int sub = 0; sub < 4; ++sub) {
            int col = c0 + sub * 16 + m;
#pragma unroll
            for (int kc = 0; kc < 4; ++kc)
                b_frag[sub][kc] = *reinterpret_cast<const bf16x8*>(
                    nb + (size_t)col * D + kc * 32 + quad * 8);
        }
#pragma unroll
        for (int sub = 0; sub < 4; ++sub) {
            floatx4 acc = {0.f, 0.f, 0.f, 0.f};
#pragma unroll
            for (int kc = 0; kc < 4; ++kc)
                acc = __builtin_amdgcn_mfma_f32_16x16x32_bf16(
                    a_frag[kc], b_frag[sub][kc], acc, 0, 0, 0);
            int jj = c0 + sub * 16 + m;  // output column for this lane
#pragma unroll
            for (int r = 0; r < 4; ++r) {
                int i = i_base + r;
                // exp(v - 2) with v = 2*acc  ->  exp2((acc-1)*2*log2e)
                float t = fmaf(acc[r], C_EXP, -C_EXP);
                float e = exp2f(t);
                if (((jj ^ i) & ~B_HALF) == 0) e = 0.f;  // j==i or j==i^4096
                l_run[r] += e;
            }
        }
    }
    // reduce the 16 columns-per-lane-group, then one atomic per row
#pragma unroll
    for (int r = 0; r < 4; ++r) {
        float s = l_run[r];
        s += __shfl_xor(s, 1, 64);
        s += __shfl_xor(s, 2, 64);
        s += __shfl_xor(s, 4, 64);
        s += __shfl_xor(s, 8, 64);
        if (m == 0) atomicAdd(&l_arr[i_base + r], s);
    }
}

// -------- kernel 3: picked logit (fp32, from raw embeddings) -------------
__global__ void k_picked(const float* __restrict__ emb,
                         const int* __restrict__ labels,
                         const float* __restrict__ rnorm,
                         float* __restrict__ accum) {
    int wv   = threadIdx.x >> 6;
    int lane = threadIdx.x & 63;
    int i = blockIdx.x * 4 + wv;
    int p = i ^ B_HALF;
    int a = min(i, p), b = max(i, p);
    int l = labels[i];
    int c = l + (l >= a);
    c += (c >= b);
    const float2* ei = reinterpret_cast<const float2*>(emb + (size_t)i * D);
    const float2* ec = reinterpret_cast<const float2*>(emb + (size_t)c * D);
    float2 x = ei[lane], y = ec[lane];
    float s = x.x * y.x + x.y * y.y;
#pragma unroll
    for (int off = 32; off >= 1; off >>= 1) s += __shfl_xor(s, off, 64);
    if (lane == 0) {
        float denom = fmaxf((1.0f / rnorm[i]) * (1.0f / rnorm[c]), 1e-8f);
        float picked = s / denom * INV_T;
        atomicAdd(accum, -picked);
    }
}

// -------- kernel 4: logz = 2 + log(l), reduce sum into accum -------------
__global__ void k_logz(const float* __restrict__ l_arr,
                       float* __restrict__ accum) {
    int idx = blockIdx.x * blockDim.x + threadIdx.x;
    float s = FIXED_MAX + logf(l_arr[idx]);
#pragma unroll
    for (int off = 32; off >= 1; off >>= 1) s += __shfl_xor(s, off, 64);
    if ((threadIdx.x & 63) == 0) atomicAdd(accum, s);
}

// -------- kernel 5: finalize ---------------------------------------------
__global__ void k_final(const float* __restrict__ accum, float* __restrict__ out) {
    if (threadIdx.x == 0) out[0] = accum[0] * (1.0f / TWO_B);
}

extern "C" void kernel_launch(void* const* d_in, const int* in_sizes, int n_in,
                              void* d_out, int out_size, void* d_ws, size_t ws_size,
                              hipStream_t stream) {
    const float* emb    = (const float*)d_in[0];
    const int*   labels = (const int*)d_in[1];
    char* ws = (char*)d_ws;
    // ws layout: rnorm[8192] f32 | l_arr[8192] f32 | accum (256B pad) | nb bf16[8192*128]
    float*  rnorm = (float*)ws;
    float*  l_arr = (float*)(ws + 32768);
    float*  accum = (float*)(ws + 65536);
    __bf16* nb    = (__bf16*)(ws + 65792);
    float*  out   = (float*)d_out;

    hipMemsetAsync(ws + 32768, 0, 32768 + 256, stream);  // zero l_arr + accum
    k_normalize<<<TWO_B / 4, 256, 0, stream>>>(emb, rnorm, nb);
    dim3 g2(TWO_B / 64, 4);
    k_simlse<<<g2, 256, 0, stream>>>(nb, l_arr);
    k_picked<<<TWO_B / 4, 256, 0, stream>>>(emb, labels, rnorm, accum);
    k_logz<<<TWO_B / 256, 256, 0, stream>>>(l_arr, accum);
    k_final<<<1, 64, 0, stream>>>(accum, out);
}

// Round 2
// 129.243 us; speedup vs baseline: 2.3173x; 2.3173x over previous
//
#include <hip/hip_runtime.h>
#include <hip/hip_bf16.h>

// NT-Xent loss, 2B=8192, D=128, T=0.5.
// sim = (N N^T) * 2 with N = row-normalized embeddings (bf16, MFMA).
// Per-row sum of exp(sim-2) over ALL columns (fixed max=2 since cos<=1);
// the j==i and j==i^4096 (positive-pair) terms are subtracted afterwards
// in k_aux from fp32 dots of the same bf16 data (error ~1e-6, no
// cancellation: l ~ 1100, corr ~ 2). picked logit in fp32 from raw emb.

typedef __bf16 bf16x8 __attribute__((ext_vector_type(8)));
typedef float floatx4 __attribute__((ext_vector_type(4)));

#define TWO_B 8192
#define B_HALF 4096
#define D 128
#define INV_T 2.0f                 // 1/temperature
#define FIXED_MAX 2.0f             // logit upper bound (cos<=1)
#define C_EXP 2.885390081777927f   // INV_T * log2(e) == FIXED_MAX * log2(e)

// ---------------- kernel 1: normalize rows, cast to bf16, zero l_arr -----
__global__ void k_normalize(const float* __restrict__ emb,
                            __bf16* __restrict__ nb,
                            float* __restrict__ l_arr) {
    int wv   = threadIdx.x >> 6;
    int lane = threadIdx.x & 63;
    int row  = blockIdx.x * 4 + wv;
    const float2* e2 = reinterpret_cast<const float2*>(emb + (size_t)row * D);
    float2 v = e2[lane];
    float ss = v.x * v.x + v.y * v.y;
#pragma unroll
    for (int off = 32; off >= 1; off >>= 1) ss += __shfl_xor(ss, off, 64);
    float rn = rsqrtf(fmaxf(ss, 1e-16f));
    union { __bf16 h[2]; unsigned int u; } pk;
    pk.h[0] = (__bf16)(v.x * rn);
    pk.h[1] = (__bf16)(v.y * rn);
    reinterpret_cast<unsigned int*>(nb)[row * 64 + lane] = pk.u;
    if (blockIdx.x < TWO_B / 256) l_arr[blockIdx.x * 256 + threadIdx.x] = 0.f;
}

// ------- kernel 2: fused Gram-matrix MFMA + unmasked exp-sum per row -----
// grid: (8192/128 row-blocks, 16 col-splits), block: 256 (4 waves x 32 rows)
__global__ __launch_bounds__(256, 4) void k_simlse(const __bf16* __restrict__ nb,
                                                   float* __restrict__ l_arr) {
    const int lane = threadIdx.x & 63;
    const int w    = threadIdx.x >> 6;
    const int m    = lane & 15;
    const int quad = lane >> 4;
    const int row0 = blockIdx.x * 128 + w * 32;   // this wave: rows row0..row0+31
    const int col0 = blockIdx.y * 512;            // this block: 512 columns

    // A fragments: two 16-row tiles, full K=128, kept in registers (32 VGPR)
    bf16x8 a0[4], a1[4];
#pragma unroll
    for (int kc = 0; kc < 4; ++kc) {
        a0[kc] = *reinterpret_cast<const bf16x8*>(
            nb + (size_t)(row0 + m) * D + kc * 32 + quad * 8);
        a1[kc] = *reinterpret_cast<const bf16x8*>(
            nb + (size_t)(row0 + 16 + m) * D + kc * 32 + quad * 8);
    }

    float l0[4] = {0.f, 0.f, 0.f, 0.f};
    float l1[4] = {0.f, 0.f, 0.f, 0.f};

    auto loadB = [&](bf16x8* buf, int sub) {
        const __bf16* bp = nb + (size_t)(col0 + sub * 16 + m) * D + quad * 8;
        buf[0] = *reinterpret_cast<const bf16x8*>(bp);
        buf[1] = *reinterpret_cast<const bf16x8*>(bp + 32);
        buf[2] = *reinterpret_cast<const bf16x8*>(bp + 64);
        buf[3] = *reinterpret_cast<const bf16x8*>(bp + 96);
    };
    auto compute = [&](const bf16x8* buf) {
        floatx4 acc0 = {0.f, 0.f, 0.f, 0.f};
        floatx4 acc1 = {0.f, 0.f, 0.f, 0.f};
#pragma unroll
        for (int kc = 0; kc < 4; ++kc) {
            acc0 = __builtin_amdgcn_mfma_f32_16x16x32_bf16(a0[kc], buf[kc], acc0, 0, 0, 0);
            acc1 = __builtin_amdgcn_mfma_f32_16x16x32_bf16(a1[kc], buf[kc], acc1, 0, 0, 0);
        }
#pragma unroll
        for (int r = 0; r < 4; ++r) {
            l0[r] += exp2f(fmaf(acc0[r], C_EXP, -C_EXP));
            l1[r] += exp2f(fmaf(acc1[r], C_EXP, -C_EXP));
        }
    };

    // ping-pong register double-buffer over 32 sub-tiles of 16 columns
    bf16x8 bufA[4], bufB[4];
    loadB(bufA, 0);
    for (int it = 0; it < 32; it += 2) {
        loadB(bufB, it + 1);
        compute(bufA);
        loadB(bufA, (it + 2) & 31);   // last one wraps (harmless reload)
        compute(bufB);
    }

    // reduce the 16 columns-per-lane-group, then one atomic per row
    const int i_base = row0 + quad * 4;
#pragma unroll
    for (int r = 0; r < 4; ++r) {
        float s = l0[r];
        s += __shfl_xor(s, 1, 64);
        s += __shfl_xor(s, 2, 64);
        s += __shfl_xor(s, 4, 64);
        s += __shfl_xor(s, 8, 64);
        if (m == 0) atomicAdd(&l_arr[i_base + r], s);
    }
#pragma unroll
    for (int r = 0; r < 4; ++r) {
        float s = l1[r];
        s += __shfl_xor(s, 1, 64);
        s += __shfl_xor(s, 2, 64);
        s += __shfl_xor(s, 4, 64);
        s += __shfl_xor(s, 8, 64);
        if (m == 0) atomicAdd(&l_arr[i_base + 16 + r], s);
    }
}

// ---- kernel 3: per-row logz (with mask correction) - picked, no atomics --
__global__ void k_aux(const float* __restrict__ emb,
                      const int* __restrict__ labels,
                      const float* __restrict__ l_arr,
                      const unsigned int* __restrict__ nbu,
                      float* __restrict__ row_val) {
    int wv   = threadIdx.x >> 6;
    int lane = threadIdx.x & 63;
    int i = blockIdx.x * 4 + wv;
    int p = i ^ B_HALF;
    // bf16 self-dot and positive-pair dot (match what the MFMA summed)
    unsigned int ux = nbu[i * 64 + lane], uy = nbu[p * 64 + lane];
    float x0 = __uint_as_float(ux << 16), x1 = __uint_as_float(ux & 0xffff0000u);
    float y0 = __uint_as_float(uy << 16), y1 = __uint_as_float(uy & 0xffff0000u);
    float dii = x0 * x0 + x1 * x1;
    float dip = x0 * y0 + x1 * y1;
    // picked logit in fp32 from raw embeddings
    int a = min(i, p), b = max(i, p);
    int l = labels[i];
    int c = l + (l >= a);
    c += (c >= b);
    const float2* ei = reinterpret_cast<const float2*>(emb + (size_t)i * D);
    const float2* ec = reinterpret_cast<const float2*>(emb + (size_t)c * D);
    float2 xe = ei[lane], ye = ec[lane];
    float dot = xe.x * ye.x + xe.y * ye.y;
    float ssi = xe.x * xe.x + xe.y * xe.y;
    float ssc = ye.x * ye.x + ye.y * ye.y;
#pragma unroll
    for (int off = 32; off >= 1; off >>= 1) {
        dii += __shfl_xor(dii, off, 64);
        dip += __shfl_xor(dip, off, 64);
        dot += __shfl_xor(dot, off, 64);
        ssi += __shfl_xor(ssi, off, 64);
        ssc += __shfl_xor(ssc, off, 64);
    }
    if (lane == 0) {
        float corr = exp2f(fmaf(dii, C_EXP, -C_EXP)) + exp2f(fmaf(dip, C_EXP, -C_EXP));
        float lv = l_arr[i] - corr;
        float logz = FIXED_MAX + logf(lv);
        float picked = dot * rsqrtf(ssi) * rsqrtf(ssc) * INV_T;
        row_val[i] = logz - picked;
    }
}

// -------- kernel 4: single-block reduce + finalize ------------------------
__global__ void k_final(const float* __restrict__ row_val, float* __restrict__ out) {
    __shared__ float sdata[4];
    int t = threadIdx.x;
    float s = 0.f;
#pragma unroll
    for (int k = 0; k < TWO_B / 256; ++k) s += row_val[t + k * 256];
#pragma unroll
    for (int off = 32; off >= 1; off >>= 1) s += __shfl_xor(s, off, 64);
    if ((t & 63) == 0) sdata[t >> 6] = s;
    __syncthreads();
    if (t == 0) out[0] = (sdata[0] + sdata[1] + sdata[2] + sdata[3]) * (1.0f / TWO_B);
}

extern "C" void kernel_launch(void* const* d_in, const int* in_sizes, int n_in,
                              void* d_out, int out_size, void* d_ws, size_t ws_size,
                              hipStream_t stream) {
    const float* emb    = (const float*)d_in[0];
    const int*   labels = (const int*)d_in[1];
    char* ws = (char*)d_ws;
    // ws layout: l_arr[8192] f32 | row_val[8192] f32 | nb bf16[8192*128]
    float*  l_arr   = (float*)ws;
    float*  row_val = (float*)(ws + 32768);
    __bf16* nb      = (__bf16*)(ws + 65536);
    float*  out     = (float*)d_out;

    k_normalize<<<TWO_B / 4, 256, 0, stream>>>(emb, nb, l_arr);
    dim3 g2(TWO_B / 128, 16);
    k_simlse<<<g2, 256, 0, stream>>>(nb, l_arr);
    k_aux<<<TWO_B / 4, 256, 0, stream>>>(emb, labels, l_arr,
                                         (const unsigned int*)nb, row_val);
    k_final<<<1, 256, 0, stream>>>(row_val, out);
}